// Round 2
// baseline (214.810 us; speedup 1.0000x reference)
//
#include <hip/hip_runtime.h>
#include <hip/hip_bf16.h>

// Types
typedef short  bf16x8 __attribute__((ext_vector_type(8)));
typedef float  f32x4  __attribute__((ext_vector_type(4)));
typedef unsigned short ushort_t;

#define BM 128
#define BN 128
#define BK 64

static __device__ inline short f2bf(float x) {
    // round-to-nearest-even f32 -> bf16 bits
    unsigned u = __builtin_bit_cast(unsigned, x);
    u += 0x7fffu + ((u >> 16) & 1u);
    return (short)(u >> 16);
}

// ---------------------------------------------------------------------------
// Gram kernel: computes strict-lower-tri masked reductions of
// clip(feats @ feats.T, -1, 1) using bf16 MFMA, fused f32->bf16 staging.
// accbuf: [0]=S0 [1]=S1 [2]=ps(sum 1+g over pmask) [3]=pc(count pmask)
// ---------------------------------------------------------------------------
__global__ __launch_bounds__(256, 2)
void gram_kernel(const float* __restrict__ feats,
                 const int* __restrict__ labels,
                 const int* __restrict__ biases,
                 float* __restrict__ accbuf,
                 int N, int D)
{
    __shared__ ushort_t As[BM * BK];   // 16 KB, XOR-swizzled rows
    __shared__ ushort_t Bs[BN * BK];   // 16 KB
    __shared__ int lab_r[BM], bia_r[BM], lab_c[BN], bia_c[BN];

    // block -> lower-triangular tile (r >= c)
    int t = blockIdx.x;
    int r = (int)((sqrtf(8.0f * (float)t + 1.0f) - 1.0f) * 0.5f);
    while ((r + 1) * (r + 2) / 2 <= t) ++r;
    while (r * (r + 1) / 2 > t) --r;
    int c = t - r * (r + 1) / 2;
    int rowbase = r * BM, colbase = c * BN;

    int tid = threadIdx.x;
    if (tid < BM) {
        lab_r[tid] = labels[rowbase + tid];
        bia_r[tid] = biases[rowbase + tid];
    } else {
        int u = tid - BM;
        lab_c[u] = labels[colbase + u];
        bia_c[u] = biases[colbase + u];
    }

    int lane = tid & 63;
    int wid  = tid >> 6;        // 4 waves
    int wr   = wid >> 1;        // 2x2 wave grid
    int wc   = wid & 1;
    int lrow = lane & 15;       // fragment row/col index
    int kgrp = lane >> 4;       // 0..3, k-group

    f32x4 acc[4][4] = {};

    for (int k0 = 0; k0 < D; k0 += BK) {
        __syncthreads();  // protect LDS (also publishes lab/bia on iter 0)

        // ---- stage 128x64 f32 -> bf16 LDS tiles (A rows, B cols) ----
        #pragma unroll
        for (int it = 0; it < 4; ++it) {
            int wlin = tid + it * 256;          // 0..1023
            int row  = wlin >> 3;               // 0..127
            int kc   = wlin & 7;                // 8 bf16 chunk
            const float* ga = feats + (size_t)(rowbase + row) * D + k0 + kc * 8;
            const float* gb = feats + (size_t)(colbase + row) * D + k0 + kc * 8;
            f32x4 a0 = *(const f32x4*)ga;
            f32x4 a1 = *(const f32x4*)(ga + 4);
            f32x4 b0 = *(const f32x4*)gb;
            f32x4 b1 = *(const f32x4*)(gb + 4);
            bf16x8 av, bv;
            #pragma unroll
            for (int e = 0; e < 4; ++e) {
                av[e]     = f2bf(a0[e]);
                av[e + 4] = f2bf(a1[e]);
                bv[e]     = f2bf(b0[e]);
                bv[e + 4] = f2bf(b1[e]);
            }
            int boff = row * (BK * 2) + ((kc * 16) ^ ((row & 7) << 4));
            *(bf16x8*)((char*)As + boff) = av;
            *(bf16x8*)((char*)Bs + boff) = bv;
        }
        __syncthreads();

        // ---- MFMA over two K=32 sub-steps ----
        #pragma unroll
        for (int kk = 0; kk < 2; ++kk) {
            bf16x8 a[4], b[4];
            #pragma unroll
            for (int m = 0; m < 4; ++m) {
                int rr = wr * 64 + m * 16 + lrow;
                int off = rr * (BK * 2) + ((kk * 64 + kgrp * 16) ^ ((rr & 7) << 4));
                a[m] = *(const bf16x8*)((const char*)As + off);
            }
            #pragma unroll
            for (int n = 0; n < 4; ++n) {
                int cc = wc * 64 + n * 16 + lrow;
                int off = cc * (BK * 2) + ((kk * 64 + kgrp * 16) ^ ((cc & 7) << 4));
                b[n] = *(const bf16x8*)((const char*)Bs + off);
            }
            #pragma unroll
            for (int m = 0; m < 4; ++m)
                #pragma unroll
                for (int n = 0; n < 4; ++n)
                    acc[m][n] = __builtin_amdgcn_mfma_f32_16x16x32_bf16(
                        a[m], b[n], acc[m][n], 0, 0, 0);
        }
    }

    // ---- epilogue: clip + masks + reduce ----
    // C/D layout: col = lane&15, row = (lane>>4)*4 + reg  [guide §3, m89/m91]
    float s0 = 0.f, s1 = 0.f, ps = 0.f, pc = 0.f;
    #pragma unroll
    for (int m = 0; m < 4; ++m) {
        #pragma unroll
        for (int e = 0; e < 4; ++e) {
            int li = wr * 64 + m * 16 + kgrp * 4 + e;
            int gi = rowbase + li;
            int labi = lab_r[li];
            int bi   = bia_r[li];
            #pragma unroll
            for (int n = 0; n < 4; ++n) {
                int lj = wc * 64 + n * 16 + lrow;
                int gj = colbase + lj;
                if (gi > gj) {
                    float g = acc[m][n][e];
                    g = fminf(fmaxf(g, -1.f), 1.f);
                    int bj = bia_c[lj];
                    if (bi == bj) {
                        if (bi == 0) s0 += g; else s1 += g;
                    } else if (labi == lab_c[lj] && bi < bj) {
                        ps += 1.f + g;
                        pc += 1.f;
                    }
                }
            }
        }
    }
    #pragma unroll
    for (int off = 32; off > 0; off >>= 1) {
        s0 += __shfl_down(s0, off);
        s1 += __shfl_down(s1, off);
        ps += __shfl_down(ps, off);
        pc += __shfl_down(pc, off);
    }
    if (lane == 0) {
        atomicAdd(&accbuf[0], s0);
        atomicAdd(&accbuf[1], s1);
        atomicAdd(&accbuf[2], ps);
        atomicAdd(&accbuf[3], pc);
    }
}

// ---------------------------------------------------------------------------
// Cross-entropy + bias-class counts.
// accbuf: [4]=sum CE  [5]=count bias==0  [6]=count bias==1
// ---------------------------------------------------------------------------
__global__ __launch_bounds__(256)
void ce_count_kernel(const float* __restrict__ logits,
                     const int* __restrict__ labels,
                     const int* __restrict__ biases,
                     float* __restrict__ accbuf,
                     int N, int C)
{
    int i = blockIdx.x * blockDim.x + threadIdx.x;
    float loss = 0.f, c0 = 0.f, c1 = 0.f;
    if (i < N) {
        const float* row = logits + (size_t)i * C;
        float mx = -INFINITY;
        for (int k = 0; k < C; ++k) mx = fmaxf(mx, row[k]);
        float s = 0.f;
        for (int k = 0; k < C; ++k) s += expf(row[k] - mx);
        loss = mx + logf(s) - row[labels[i]];
        if (biases[i] == 0) c0 = 1.f; else c1 = 1.f;
    }
    #pragma unroll
    for (int off = 32; off > 0; off >>= 1) {
        loss += __shfl_down(loss, off);
        c0   += __shfl_down(c0, off);
        c1   += __shfl_down(c1, off);
    }
    if ((threadIdx.x & 63) == 0) {
        atomicAdd(&accbuf[4], loss);
        atomicAdd(&accbuf[5], c0);
        atomicAdd(&accbuf[6], c1);
    }
}

// ---------------------------------------------------------------------------
// Finalize: combine accumulators into the two outputs (float32).
// ---------------------------------------------------------------------------
__global__ void finalize_kernel(const float* __restrict__ accbuf,
                                float* __restrict__ out, int N)
{
    float S0 = accbuf[0], S1 = accbuf[1], ps = accbuf[2], pc = accbuf[3];
    float ce = accbuf[4], n0 = accbuf[5], n1 = accbuf[6];
    float Mo = 0.5f * (n0 * (n0 - 1.f) + n1 * (n1 - 1.f));
    float Ro = (Mo > 0.f) ? (fabsf(S0) + fabsf(S1)) / Mo : 0.f;
    float Rp = (pc > 0.f) ? 1.f + (-0.5f * ps) / pc : 0.f;
    out[0] = ce / (float)N;
    out[1] = Ro + Rp;   // ALPHA=BETA=1
}

extern "C" void kernel_launch(void* const* d_in, const int* in_sizes, int n_in,
                              void* d_out, int out_size, void* d_ws, size_t ws_size,
                              hipStream_t stream)
{
    const float* logits = (const float*)d_in[0];
    const int*   labels = (const int*)d_in[1];
    const int*   biases = (const int*)d_in[2];
    const float* feats  = (const float*)d_in[3];

    int N = in_sizes[1];              // 4096
    int C = in_sizes[0] / N;          // 10
    int D = in_sizes[3] / N;          // 2048

    float* accbuf = (float*)d_ws;
    hipMemsetAsync(accbuf, 0, 8 * sizeof(float), stream);

    int nt = N / BM;                  // 32
    int T  = nt * (nt + 1) / 2;       // 528 lower-tri tiles
    gram_kernel<<<T, 256, 0, stream>>>(feats, labels, biases, accbuf, N, D);
    ce_count_kernel<<<(N + 255) / 256, 256, 0, stream>>>(logits, labels, biases,
                                                         accbuf, N, C);
    finalize_kernel<<<1, 1, 0, stream>>>(accbuf, (float*)d_out, N);
}

// Round 3
// 203.492 us; speedup vs baseline: 1.0556x; 1.0556x over previous
//
#include <hip/hip_runtime.h>
#include <hip/hip_bf16.h>

// Types
typedef short  bf16x8 __attribute__((ext_vector_type(8)));
typedef float  f32x4  __attribute__((ext_vector_type(4)));
typedef unsigned short ushort_t;

#define BM 128
#define BN 128
#define BK 64

#define GLD_LDS16(gp, lp) __builtin_amdgcn_global_load_lds(                 \
    (const __attribute__((address_space(1))) void*)(gp),                    \
    (__attribute__((address_space(3))) void*)(lp), 16, 0, 0)

static __device__ inline short f2bf(float x) {
    // round-to-nearest-even f32 -> bf16 bits
    unsigned u = __builtin_bit_cast(unsigned, x);
    u += 0x7fffu + ((u >> 16) & 1u);
    return (short)(u >> 16);
}

// ---------------------------------------------------------------------------
// Pre-pass: feats f32 -> bf16 (memory-bound, ~48 MB traffic)
// ---------------------------------------------------------------------------
__global__ __launch_bounds__(256)
void convert_kernel(const float* __restrict__ in, ushort_t* __restrict__ out,
                    int n)
{
    int i = (blockIdx.x * blockDim.x + threadIdx.x) * 8;
    if (i < n) {
        f32x4 a = *(const f32x4*)(in + i);
        f32x4 b = *(const f32x4*)(in + i + 4);
        bf16x8 v;
        #pragma unroll
        for (int e = 0; e < 4; ++e) {
            v[e]     = f2bf(a[e]);
            v[e + 4] = f2bf(b[e]);
        }
        *(bf16x8*)(out + i) = v;
    }
}

// ---------------------------------------------------------------------------
// Gram kernel (fast path): bf16 feats, global_load_lds staging, 2-phase
// double-buffered pipeline. LDS image is XOR-swizzled via pre-swizzled
// global source (rule #21): content at byte row*128 + kc*16 is global
// chunk kc ^ (row&7)  ==  swizzled write of previous round (read code
// unchanged, bank-conflict-free).
// accbuf: [0]=S0 [1]=S1 [2]=ps [3]=pc
// ---------------------------------------------------------------------------
__global__ __launch_bounds__(256, 2)
void gram_lds_kernel(const ushort_t* __restrict__ fb,
                     const int* __restrict__ labels,
                     const int* __restrict__ biases,
                     float* __restrict__ accbuf,
                     int N, int D)
{
    __shared__ ushort_t lds[2][2][BM * BK];   // 64 KB: [buf][A/B][tile]
    __shared__ int lab_r[BM], bia_r[BM], lab_c[BN], bia_c[BN];

    // block -> lower-triangular tile (r >= c)
    int t = blockIdx.x;
    int r = (int)((sqrtf(8.0f * (float)t + 1.0f) - 1.0f) * 0.5f);
    while ((r + 1) * (r + 2) / 2 <= t) ++r;
    while (r * (r + 1) / 2 > t) --r;
    int c = t - r * (r + 1) / 2;
    int rowbase = r * BM, colbase = c * BN;

    int tid = threadIdx.x;
    if (tid < BM) {
        lab_r[tid] = labels[rowbase + tid];
        bia_r[tid] = biases[rowbase + tid];
    } else {
        int u = tid - BM;
        lab_c[u] = labels[colbase + u];
        bia_c[u] = biases[colbase + u];
    }

    int lane = tid & 63;
    int wid  = tid >> 6;        // 4 waves
    int wr   = wid >> 1;        // 2x2 wave grid
    int wc   = wid & 1;
    int lrow = lane & 15;
    int kgrp = lane >> 4;

    // staging: 1024 chunks of 16B per tile; chunk j -> row j>>3, slot j&7;
    // source chunk index pre-swizzled so LDS image matches swizzled reads.
    auto STAGE = [&](int k0, int buf) {
        ushort_t* Ab = &lds[buf][0][0];
        ushort_t* Bb = &lds[buf][1][0];
        #pragma unroll
        for (int i = 0; i < 4; ++i) {
            int j   = i * 256 + tid;           // wave-contiguous chunks
            int row = j >> 3;
            int kc  = (j & 7) ^ (row & 7);     // pre-swizzled source slot
            const ushort_t* ga = fb + (size_t)(rowbase + row) * D + k0 + kc * 8;
            const ushort_t* gb = fb + (size_t)(colbase + row) * D + k0 + kc * 8;
            GLD_LDS16(ga, Ab + j * 8);
            GLD_LDS16(gb, Bb + j * 8);
        }
    };

    f32x4 acc[4][4] = {};

    STAGE(0, 0);
    __syncthreads();            // compiler drains vmcnt(0) before barrier

    int cur = 0;
    for (int k0 = 0; k0 < D; k0 += BK) {
        if (k0 + BK < D) STAGE(k0 + BK, cur ^ 1);

        const ushort_t* Ab = &lds[cur][0][0];
        const ushort_t* Bb = &lds[cur][1][0];
        #pragma unroll
        for (int kk = 0; kk < 2; ++kk) {
            bf16x8 a[4], b[4];
            #pragma unroll
            for (int m = 0; m < 4; ++m) {
                int rr = wr * 64 + m * 16 + lrow;
                int off = rr * (BK * 2) + ((kk * 64 + kgrp * 16) ^ ((rr & 7) << 4));
                a[m] = *(const bf16x8*)((const char*)Ab + off);
            }
            #pragma unroll
            for (int n = 0; n < 4; ++n) {
                int cc = wc * 64 + n * 16 + lrow;
                int off = cc * (BK * 2) + ((kk * 64 + kgrp * 16) ^ ((cc & 7) << 4));
                b[n] = *(const bf16x8*)((const char*)Bb + off);
            }
            #pragma unroll
            for (int m = 0; m < 4; ++m)
                #pragma unroll
                for (int n = 0; n < 4; ++n)
                    acc[m][n] = __builtin_amdgcn_mfma_f32_16x16x32_bf16(
                        a[m], b[n], acc[m][n], 0, 0, 0);
        }
        __syncthreads();        // drains vmcnt(0): next buffer ready
        cur ^= 1;
    }

    // ---- epilogue: clip + masks + reduce ----
    // C/D layout: col = lane&15, row = (lane>>4)*4 + reg
    float s0 = 0.f, s1 = 0.f, ps = 0.f, pc = 0.f;
    #pragma unroll
    for (int m = 0; m < 4; ++m) {
        #pragma unroll
        for (int e = 0; e < 4; ++e) {
            int li = wr * 64 + m * 16 + kgrp * 4 + e;
            int gi = rowbase + li;
            int labi = lab_r[li];
            int bi   = bia_r[li];
            #pragma unroll
            for (int n = 0; n < 4; ++n) {
                int lj = wc * 64 + n * 16 + lrow;
                int gj = colbase + lj;
                if (gi > gj) {
                    float g = acc[m][n][e];
                    g = fminf(fmaxf(g, -1.f), 1.f);
                    int bj = bia_c[lj];
                    if (bi == bj) {
                        if (bi == 0) s0 += g; else s1 += g;
                    } else if (labi == lab_c[lj] && bi < bj) {
                        ps += 1.f + g;
                        pc += 1.f;
                    }
                }
            }
        }
    }
    #pragma unroll
    for (int off = 32; off > 0; off >>= 1) {
        s0 += __shfl_down(s0, off);
        s1 += __shfl_down(s1, off);
        ps += __shfl_down(ps, off);
        pc += __shfl_down(pc, off);
    }
    if (lane == 0) {
        atomicAdd(&accbuf[0], s0);
        atomicAdd(&accbuf[1], s1);
        atomicAdd(&accbuf[2], ps);
        atomicAdd(&accbuf[3], pc);
    }
}

// ---------------------------------------------------------------------------
// Gram kernel (fallback, ws too small): fused f32->bf16 staging (R2 version)
// ---------------------------------------------------------------------------
__global__ __launch_bounds__(256, 2)
void gram_fused_kernel(const float* __restrict__ feats,
                       const int* __restrict__ labels,
                       const int* __restrict__ biases,
                       float* __restrict__ accbuf,
                       int N, int D)
{
    __shared__ ushort_t As[BM * BK];
    __shared__ ushort_t Bs[BN * BK];
    __shared__ int lab_r[BM], bia_r[BM], lab_c[BN], bia_c[BN];

    int t = blockIdx.x;
    int r = (int)((sqrtf(8.0f * (float)t + 1.0f) - 1.0f) * 0.5f);
    while ((r + 1) * (r + 2) / 2 <= t) ++r;
    while (r * (r + 1) / 2 > t) --r;
    int c = t - r * (r + 1) / 2;
    int rowbase = r * BM, colbase = c * BN;

    int tid = threadIdx.x;
    if (tid < BM) {
        lab_r[tid] = labels[rowbase + tid];
        bia_r[tid] = biases[rowbase + tid];
    } else {
        int u = tid - BM;
        lab_c[u] = labels[colbase + u];
        bia_c[u] = biases[colbase + u];
    }

    int lane = tid & 63;
    int wid  = tid >> 6;
    int wr   = wid >> 1;
    int wc   = wid & 1;
    int lrow = lane & 15;
    int kgrp = lane >> 4;

    f32x4 acc[4][4] = {};

    for (int k0 = 0; k0 < D; k0 += BK) {
        __syncthreads();
        #pragma unroll
        for (int it = 0; it < 4; ++it) {
            int wlin = tid + it * 256;
            int row  = wlin >> 3;
            int kc   = wlin & 7;
            const float* ga = feats + (size_t)(rowbase + row) * D + k0 + kc * 8;
            const float* gb = feats + (size_t)(colbase + row) * D + k0 + kc * 8;
            f32x4 a0 = *(const f32x4*)ga;
            f32x4 a1 = *(const f32x4*)(ga + 4);
            f32x4 b0 = *(const f32x4*)gb;
            f32x4 b1 = *(const f32x4*)(gb + 4);
            bf16x8 av, bv;
            #pragma unroll
            for (int e = 0; e < 4; ++e) {
                av[e]     = f2bf(a0[e]);
                av[e + 4] = f2bf(a1[e]);
                bv[e]     = f2bf(b0[e]);
                bv[e + 4] = f2bf(b1[e]);
            }
            int boff = row * (BK * 2) + ((kc * 16) ^ ((row & 7) << 4));
            *(bf16x8*)((char*)As + boff) = av;
            *(bf16x8*)((char*)Bs + boff) = bv;
        }
        __syncthreads();

        #pragma unroll
        for (int kk = 0; kk < 2; ++kk) {
            bf16x8 a[4], b[4];
            #pragma unroll
            for (int m = 0; m < 4; ++m) {
                int rr = wr * 64 + m * 16 + lrow;
                int off = rr * (BK * 2) + ((kk * 64 + kgrp * 16) ^ ((rr & 7) << 4));
                a[m] = *(const bf16x8*)((const char*)As + off);
            }
            #pragma unroll
            for (int n = 0; n < 4; ++n) {
                int cc = wc * 64 + n * 16 + lrow;
                int off = cc * (BK * 2) + ((kk * 64 + kgrp * 16) ^ ((cc & 7) << 4));
                b[n] = *(const bf16x8*)((const char*)Bs + off);
            }
            #pragma unroll
            for (int m = 0; m < 4; ++m)
                #pragma unroll
                for (int n = 0; n < 4; ++n)
                    acc[m][n] = __builtin_amdgcn_mfma_f32_16x16x32_bf16(
                        a[m], b[n], acc[m][n], 0, 0, 0);
        }
    }

    float s0 = 0.f, s1 = 0.f, ps = 0.f, pc = 0.f;
    #pragma unroll
    for (int m = 0; m < 4; ++m) {
        #pragma unroll
        for (int e = 0; e < 4; ++e) {
            int li = wr * 64 + m * 16 + kgrp * 4 + e;
            int gi = rowbase + li;
            int labi = lab_r[li];
            int bi   = bia_r[li];
            #pragma unroll
            for (int n = 0; n < 4; ++n) {
                int lj = wc * 64 + n * 16 + lrow;
                int gj = colbase + lj;
                if (gi > gj) {
                    float g = acc[m][n][e];
                    g = fminf(fmaxf(g, -1.f), 1.f);
                    int bj = bia_c[lj];
                    if (bi == bj) {
                        if (bi == 0) s0 += g; else s1 += g;
                    } else if (labi == lab_c[lj] && bi < bj) {
                        ps += 1.f + g;
                        pc += 1.f;
                    }
                }
            }
        }
    }
    #pragma unroll
    for (int off = 32; off > 0; off >>= 1) {
        s0 += __shfl_down(s0, off);
        s1 += __shfl_down(s1, off);
        ps += __shfl_down(ps, off);
        pc += __shfl_down(pc, off);
    }
    if (lane == 0) {
        atomicAdd(&accbuf[0], s0);
        atomicAdd(&accbuf[1], s1);
        atomicAdd(&accbuf[2], ps);
        atomicAdd(&accbuf[3], pc);
    }
}

// ---------------------------------------------------------------------------
// Cross-entropy + bias-class counts.  accbuf: [4]=CE sum [5]=n0 [6]=n1
// ---------------------------------------------------------------------------
__global__ __launch_bounds__(256)
void ce_count_kernel(const float* __restrict__ logits,
                     const int* __restrict__ labels,
                     const int* __restrict__ biases,
                     float* __restrict__ accbuf,
                     int N, int C)
{
    int i = blockIdx.x * blockDim.x + threadIdx.x;
    float loss = 0.f, c0 = 0.f, c1 = 0.f;
    if (i < N) {
        const float* row = logits + (size_t)i * C;
        float mx = -INFINITY;
        for (int k = 0; k < C; ++k) mx = fmaxf(mx, row[k]);
        float s = 0.f;
        for (int k = 0; k < C; ++k) s += expf(row[k] - mx);
        loss = mx + logf(s) - row[labels[i]];
        if (biases[i] == 0) c0 = 1.f; else c1 = 1.f;
    }
    #pragma unroll
    for (int off = 32; off > 0; off >>= 1) {
        loss += __shfl_down(loss, off);
        c0   += __shfl_down(c0, off);
        c1   += __shfl_down(c1, off);
    }
    if ((threadIdx.x & 63) == 0) {
        atomicAdd(&accbuf[4], loss);
        atomicAdd(&accbuf[5], c0);
        atomicAdd(&accbuf[6], c1);
    }
}

// ---------------------------------------------------------------------------
// Finalize
// ---------------------------------------------------------------------------
__global__ void finalize_kernel(const float* __restrict__ accbuf,
                                float* __restrict__ out, int N)
{
    float S0 = accbuf[0], S1 = accbuf[1], ps = accbuf[2], pc = accbuf[3];
    float ce = accbuf[4], n0 = accbuf[5], n1 = accbuf[6];
    float Mo = 0.5f * (n0 * (n0 - 1.f) + n1 * (n1 - 1.f));
    float Ro = (Mo > 0.f) ? (fabsf(S0) + fabsf(S1)) / Mo : 0.f;
    float Rp = (pc > 0.f) ? 1.f + (-0.5f * ps) / pc : 0.f;
    out[0] = ce / (float)N;
    out[1] = Ro + Rp;   // ALPHA=BETA=1
}

extern "C" void kernel_launch(void* const* d_in, const int* in_sizes, int n_in,
                              void* d_out, int out_size, void* d_ws, size_t ws_size,
                              hipStream_t stream)
{
    const float* logits = (const float*)d_in[0];
    const int*   labels = (const int*)d_in[1];
    const int*   biases = (const int*)d_in[2];
    const float* feats  = (const float*)d_in[3];

    int N = in_sizes[1];              // 4096
    int C = in_sizes[0] / N;          // 10
    int D = in_sizes[3] / N;          // 2048

    float* accbuf = (float*)d_ws;
    hipMemsetAsync(accbuf, 0, 8 * sizeof(float), stream);

    int nt = N / BM;                  // 32
    int T  = nt * (nt + 1) / 2;       // 528 lower-tri tiles

    size_t need = 256 + (size_t)N * D * sizeof(ushort_t);   // 16 MB + hdr
    if (ws_size >= need) {
        ushort_t* fb = (ushort_t*)((char*)d_ws + 256);
        int nconv = N * D;
        convert_kernel<<<(nconv / 8 + 255) / 256, 256, 0, stream>>>(feats, fb,
                                                                    nconv);
        gram_lds_kernel<<<T, 256, 0, stream>>>(fb, labels, biases, accbuf, N, D);
    } else {
        gram_fused_kernel<<<T, 256, 0, stream>>>(feats, labels, biases, accbuf,
                                                 N, D);
    }
    ce_count_kernel<<<(N + 255) / 256, 256, 0, stream>>>(logits, labels, biases,
                                                         accbuf, N, C);
    finalize_kernel<<<1, 1, 0, stream>>>(accbuf, (float*)d_out, N);
}